// Round 4
// baseline (59.299 us; speedup 1.0000x reference)
//
#include <hip/hip_runtime.h>
#include <hip/hip_cooperative_groups.h>

namespace cg = cooperative_groups;

// HistogramEqualization: reference collapses to out = x * hist[1]/(N - hist[0])
// because jnp.interp(x in [0,1], arange(256), cdfn) only uses cdfn[0..1] and
// cdfn[0] == 0 (cdf.min() == cdf[0]).
//
// R4: single cooperative kernel, register-resident payload (24 float4/thread,
// grid 1024x256 exactly covers n=25165824). Eliminates the second 100MB read
// and one launch. Count -> grid.sync -> reduce partials -> scale regs -> store.
// Fallback two-kernel path (count 8-way, apply 8-way) for any other n or if
// occupancy is insufficient for a cooperative launch.

#define FGRID 1024
#define FBLOCK 256
#define CHUNK 24  // float4 per thread; requires n4 == FGRID*FBLOCK*CHUNK

__global__ __launch_bounds__(FBLOCK, 4) void histeq_fused(
    const float4* __restrict__ x4, float4* __restrict__ out4,
    unsigned long long* __restrict__ partials, int n_total) {
    const int tid = blockIdx.x * FBLOCK + threadIdx.x;
    const int stride = FGRID * FBLOCK;

    // Phase 1: load everything into registers (24 loads in flight), count.
    float4 v[CHUNK];
#pragma unroll
    for (int k = 0; k < CHUNK; ++k) v[k] = x4[tid + k * stride];

    unsigned int c0 = 0, c1 = 0;
#pragma unroll
    for (int k = 0; k < CHUNK; ++k) {
        // (int)(f*256.0f) is exact for f in [0,1]: *256 is an exponent shift.
        int b0 = (int)(v[k].x * 256.0f);
        int b1 = (int)(v[k].y * 256.0f);
        int b2 = (int)(v[k].z * 256.0f);
        int b3 = (int)(v[k].w * 256.0f);
        c0 += (unsigned)(b0 == 0) + (unsigned)(b1 == 0) + (unsigned)(b2 == 0) + (unsigned)(b3 == 0);
        c1 += (unsigned)(b0 == 1) + (unsigned)(b1 == 1) + (unsigned)(b2 == 1) + (unsigned)(b3 == 1);
    }
#pragma unroll
    for (int off = 32; off > 0; off >>= 1) {
        c0 += __shfl_down(c0, off, 64);
        c1 += __shfl_down(c1, off, 64);
    }
    __shared__ unsigned int sm0[4], sm1[4];
    __shared__ float s_scale;
    const int lane = threadIdx.x & 63;
    const int wid = threadIdx.x >> 6;
    if (lane == 0) { sm0[wid] = c0; sm1[wid] = c1; }
    __syncthreads();
    if (threadIdx.x == 0) {
        unsigned long long t0 = sm0[0] + sm0[1] + sm0[2] + sm0[3];
        unsigned long long t1 = sm1[0] + sm1[1] + sm1[2] + sm1[3];
        partials[blockIdx.x] = t0 | (t1 << 32);
    }

    cg::this_grid().sync();  // device-scope fence: partials visible grid-wide

    // Phase 2: every block reduces the 1024 partials (8 KB, L2-resident).
    unsigned int t0 = 0, t1 = 0;
    for (int j = threadIdx.x; j < FGRID; j += FBLOCK) {
        unsigned long long p = partials[j];
        t0 += (unsigned int)(p & 0xFFFFFFFFull);
        t1 += (unsigned int)(p >> 32);
    }
#pragma unroll
    for (int off = 32; off > 0; off >>= 1) {
        t0 += __shfl_down(t0, off, 64);
        t1 += __shfl_down(t1, off, 64);
    }
    if (lane == 0) { sm0[wid] = t0; sm1[wid] = t1; }
    __syncthreads();
    if (threadIdx.x == 0) {
        double h0 = (double)(sm0[0] + sm0[1] + sm0[2] + sm0[3]);
        double h1 = (double)(sm1[0] + sm1[1] + sm1[2] + sm1[3]);
        s_scale = (float)(h1 / ((double)n_total - h0));
    }
    __syncthreads();
    const float s = s_scale;

    // Phase 3: scale registers, store.
#pragma unroll
    for (int k = 0; k < CHUNK; ++k) {
        float4 o;
        o.x = v[k].x * s;
        o.y = v[k].y * s;
        o.z = v[k].z * s;
        o.w = v[k].w * s;
        out4[tid + k * stride] = o;
    }
}

// ---------------- fallback path (generic n) ----------------

__global__ __launch_bounds__(256) void histeq_count(const float4* __restrict__ x4,
                                                    unsigned long long* __restrict__ partials,
                                                    int n4, const float* __restrict__ x,
                                                    int n) {
    unsigned int c0 = 0, c1 = 0;
    const int tid = blockIdx.x * blockDim.x + threadIdx.x;
    const int stride = gridDim.x * blockDim.x;

    int i = tid;
    for (; i + 7 * stride < n4; i += 8 * stride) {
        float4 v[8];
#pragma unroll
        for (int k = 0; k < 8; ++k) v[k] = x4[i + k * stride];
#pragma unroll
        for (int k = 0; k < 8; ++k) {
            int b0 = (int)(v[k].x * 256.0f);
            int b1 = (int)(v[k].y * 256.0f);
            int b2 = (int)(v[k].z * 256.0f);
            int b3 = (int)(v[k].w * 256.0f);
            c0 += (unsigned)(b0 == 0) + (unsigned)(b1 == 0) + (unsigned)(b2 == 0) + (unsigned)(b3 == 0);
            c1 += (unsigned)(b0 == 1) + (unsigned)(b1 == 1) + (unsigned)(b2 == 1) + (unsigned)(b3 == 1);
        }
    }
    for (; i < n4; i += stride) {
        float4 v = x4[i];
        int b0 = (int)(v.x * 256.0f);
        int b1 = (int)(v.y * 256.0f);
        int b2 = (int)(v.z * 256.0f);
        int b3 = (int)(v.w * 256.0f);
        c0 += (unsigned)(b0 == 0) + (unsigned)(b1 == 0) + (unsigned)(b2 == 0) + (unsigned)(b3 == 0);
        c1 += (unsigned)(b0 == 1) + (unsigned)(b1 == 1) + (unsigned)(b2 == 1) + (unsigned)(b3 == 1);
    }
    if (blockIdx.x == 0 && threadIdx.x == 0) {
        for (int j = n4 * 4; j < n; ++j) {
            int b = (int)(x[j] * 256.0f);
            c0 += (unsigned)(b == 0);
            c1 += (unsigned)(b == 1);
        }
    }
#pragma unroll
    for (int off = 32; off > 0; off >>= 1) {
        c0 += __shfl_down(c0, off, 64);
        c1 += __shfl_down(c1, off, 64);
    }
    __shared__ unsigned int sm0[4], sm1[4];
    int lane = threadIdx.x & 63;
    int wid = threadIdx.x >> 6;
    if (lane == 0) { sm0[wid] = c0; sm1[wid] = c1; }
    __syncthreads();
    if (threadIdx.x == 0) {
        unsigned long long t0 = sm0[0] + sm0[1] + sm0[2] + sm0[3];
        unsigned long long t1 = sm1[0] + sm1[1] + sm1[2] + sm1[3];
        partials[blockIdx.x] = t0 | (t1 << 32);
    }
}

__global__ __launch_bounds__(256) void histeq_apply(const float4* __restrict__ x4,
                                                    float4* __restrict__ out4,
                                                    const unsigned long long* __restrict__ partials,
                                                    int nparts,
                                                    int n4, int n_total,
                                                    const float* __restrict__ x,
                                                    float* __restrict__ out) {
    unsigned int c0 = 0, c1 = 0;
    for (int j = threadIdx.x; j < nparts; j += blockDim.x) {
        unsigned long long p = partials[j];
        c0 += (unsigned int)(p & 0xFFFFFFFFull);
        c1 += (unsigned int)(p >> 32);
    }
#pragma unroll
    for (int off = 32; off > 0; off >>= 1) {
        c0 += __shfl_down(c0, off, 64);
        c1 += __shfl_down(c1, off, 64);
    }
    __shared__ unsigned int sm0[4], sm1[4];
    __shared__ float s_scale;
    int lane = threadIdx.x & 63;
    int wid = threadIdx.x >> 6;
    if (lane == 0) { sm0[wid] = c0; sm1[wid] = c1; }
    __syncthreads();
    if (threadIdx.x == 0) {
        double h0 = (double)(sm0[0] + sm0[1] + sm0[2] + sm0[3]);
        double h1 = (double)(sm1[0] + sm1[1] + sm1[2] + sm1[3]);
        s_scale = (float)(h1 / ((double)n_total - h0));
    }
    __syncthreads();
    const float s = s_scale;
    const int tid = blockIdx.x * blockDim.x + threadIdx.x;
    const int stride = gridDim.x * blockDim.x;

    int i = tid;
    for (; i + 7 * stride < n4; i += 8 * stride) {
        float4 v[8];
#pragma unroll
        for (int k = 0; k < 8; ++k) v[k] = x4[i + k * stride];
#pragma unroll
        for (int k = 0; k < 8; ++k) {
            float4 o;
            o.x = v[k].x * s;
            o.y = v[k].y * s;
            o.z = v[k].z * s;
            o.w = v[k].w * s;
            out4[i + k * stride] = o;
        }
    }
    for (; i < n4; i += stride) {
        float4 v = x4[i];
        float4 o;
        o.x = v.x * s;
        o.y = v.y * s;
        o.z = v.z * s;
        o.w = v.w * s;
        out4[i] = o;
    }
    if (blockIdx.x == 0 && threadIdx.x == 0) {
        for (int j = n4 * 4; j < n_total; ++j) out[j] = x[j] * s;
    }
}

extern "C" void kernel_launch(void* const* d_in, const int* in_sizes, int n_in,
                              void* d_out, int out_size, void* d_ws, size_t ws_size,
                              hipStream_t stream) {
    const float* x = (const float*)d_in[0];
    float* out = (float*)d_out;
    int n = in_sizes[0];
    int n4 = n >> 2;
    unsigned long long* partials = (unsigned long long*)d_ws;

    bool exact = (n == n4 * 4) && (n4 == FGRID * FBLOCK * CHUNK) &&
                 (ws_size >= FGRID * sizeof(unsigned long long));
    if (exact) {
        int nb = 0;
        hipError_t e = hipOccupancyMaxActiveBlocksPerMultiprocessor(
            &nb, histeq_fused, FBLOCK, 0);
        if (e == hipSuccess && nb >= 4) {  // 4 blocks/CU x 256 CUs >= 1024 co-resident
            void* args[] = {(void*)&x, (void*)&out, (void*)&partials, (void*)&n};
            hipLaunchCooperativeKernel((void*)histeq_fused, dim3(FGRID), dim3(FBLOCK),
                                       args, 0, stream);
            return;
        }
    }

    const int block = 256;
    int grid = 2048;
    int need = (n4 + block - 1) / block;
    if (grid > need) grid = need;
    if (grid < 1) grid = 1;

    histeq_count<<<grid, block, 0, stream>>>((const float4*)x, partials, n4, x, n);
    histeq_apply<<<grid, block, 0, stream>>>((const float4*)x, (float4*)out, partials,
                                             grid, n4, n, x, out);
}